// Round 3
// baseline (292.513 us; speedup 1.0000x reference)
//
#include <hip/hip_runtime.h>
#include <hip/hip_bf16.h>

#define BB 16
#define NN 1024
#define DIN 64
#define KK 8
#define DP 64

typedef __bf16 bf16x8 __attribute__((ext_vector_type(8)));
typedef float f32x4 __attribute__((ext_vector_type(4)));
typedef float f32x16 __attribute__((ext_vector_type(16)));

// ws layout: z bf16 [K][B*N][DP]  = 8*16384*64*2 B = 16 MiB at offset 0
//            Wt bf16 [K][DP][DIN] = 64 KiB at offset 16 MiB
#define Z_BYTES (16777216UL)

// ---------------------------------------------------------------------------
// Kernel 0: Wt[k][e][d] = bf16(W[k][d][e])   (8 blocks, one per k)
// ---------------------------------------------------------------------------
__global__ __launch_bounds__(256) void wt_kernel(const float* __restrict__ W,
                                                 __hip_bfloat16* __restrict__ Wt)
{
    __shared__ float Wl[DIN * DP];
    const int k = blockIdx.x;
    const int tid = threadIdx.x;

    const float4* src = (const float4*)(W + (size_t)k * DIN * DP);
    float4* dst = (float4*)Wl;
    #pragma unroll
    for (int i = 0; i < 4; ++i) dst[tid + i * 256] = src[tid + i * 256];
    __syncthreads();

    const int e  = tid >> 2;          // 0..63
    const int dc = (tid & 3) * 16;    // d-chunk
    __hip_bfloat16 v[16];
    #pragma unroll
    for (int i = 0; i < 16; ++i)
        v[i] = __float2bfloat16(Wl[(dc + i) * DP + e]);
    *(uint4*)(Wt + ((size_t)k * DP + e) * DIN + dc)     = *(uint4*)&v[0];
    *(uint4*)(Wt + ((size_t)k * DP + e) * DIN + dc + 8) = *(uint4*)&v[8];
}

// ---------------------------------------------------------------------------
// Kernel 1: z[k][row][e] = relu(sum_d x[row][d] * W[k][d][e] + bias[k][e]), bf16
// (unchanged from round 2 — passed, MFMA-based)
// ---------------------------------------------------------------------------
__global__ __launch_bounds__(256) void enc_kernel(const float* __restrict__ x,
                                                  const __hip_bfloat16* __restrict__ Wt,
                                                  const float* __restrict__ bias,
                                                  __hip_bfloat16* __restrict__ z)
{
    const int tid  = threadIdx.x;
    const int lane = tid & 63;
    const int wid  = tid >> 6;
    const int l31  = lane & 31;
    const int h    = lane >> 5;
    const int row0 = blockIdx.x * 32;
    const int row  = row0 + l31;

    bf16x8 xb[4];
    #pragma unroll
    for (int kk = 0; kk < 4; ++kk) {
        const float* xp = x + (size_t)row * DIN + kk * 16 + h * 8;
        float4 lo = *(const float4*)xp;
        float4 hi = *(const float4*)(xp + 4);
        bf16x8 t;
        t[0] = (__bf16)lo.x; t[1] = (__bf16)lo.y; t[2] = (__bf16)lo.z; t[3] = (__bf16)lo.w;
        t[4] = (__bf16)hi.x; t[5] = (__bf16)hi.y; t[6] = (__bf16)hi.z; t[7] = (__bf16)hi.w;
        xb[kk] = t;
    }

    #pragma unroll
    for (int a = 0; a < 2; ++a) {
        const int k = wid * 2 + a;
        #pragma unroll
        for (int et = 0; et < 2; ++et) {
            f32x16 acc;
            #pragma unroll
            for (int i = 0; i < 16; ++i) acc[i] = 0.0f;
            const __hip_bfloat16* wp =
                Wt + ((size_t)k * DP + et * 32 + l31) * DIN + h * 8;
            #pragma unroll
            for (int kk = 0; kk < 4; ++kk) {
                bf16x8 wf = *(const bf16x8*)(wp + kk * 16);
                acc = __builtin_amdgcn_mfma_f32_32x32x16_bf16(wf, xb[kk], acc, 0, 0, 0);
            }
            #pragma unroll
            for (int g = 0; g < 4; ++g) {
                const int e0 = et * 32 + 8 * g + 4 * h;
                float4 b4 = *(const float4*)(bias + k * DP + e0);
                union { __hip_bfloat16 b[4]; uint2 u; } pk;
                pk.b[0] = __float2bfloat16(fmaxf(acc[g * 4 + 0] + b4.x, 0.0f));
                pk.b[1] = __float2bfloat16(fmaxf(acc[g * 4 + 1] + b4.y, 0.0f));
                pk.b[2] = __float2bfloat16(fmaxf(acc[g * 4 + 2] + b4.z, 0.0f));
                pk.b[3] = __float2bfloat16(fmaxf(acc[g * 4 + 3] + b4.w, 0.0f));
                *(uint2*)(z + ((size_t)k * BB * NN + row) * DP + e0) = pk.u;
            }
        }
    }
}

// ---------------------------------------------------------------------------
// Kernel 2: R[b][n][m][k] = sum_e z[k][b][n][e] * z[k][b][m][e]
// mfma_f32_16x16x32_bf16: wave = 16n x 16m x ALL 8 k, acc = 8 x f32x4 = only
// 32 VGPRs (vs 128 in round 2) -> high occupancy AND direct k-contiguous
// register stores (2x dwordx4 per (n,m)), no LDS, no barrier.
// A/B frag: row = lane&15, e-chunk = (lane>>4)*8 (4 lanes cover 64 contiguous
// bytes of a z row -> full-line loads). Gram symmetry cancels k-slot perms.
// C/D (m89-verified): m = lane&15, n = (lane>>4)*4 + reg.
// Block = 4 waves in 2x2 (32x32 tile). Grid = 16*32*32 = 16384.
// ---------------------------------------------------------------------------
__global__ __launch_bounds__(256) void gram_kernel(const __hip_bfloat16* __restrict__ z,
                                                   float* __restrict__ out)
{
    const int bid = blockIdx.x;
    const int mt  = bid & 31;
    const int nt  = (bid >> 5) & 31;
    const int b   = bid >> 10;
    const int tid  = threadIdx.x;
    const int lane = tid & 63;
    const int wid  = tid >> 6;
    const int l15  = lane & 15;
    const int q    = lane >> 4;       // 0..3: e-chunk selector / n-subrow

    const int n0 = nt * 32 + (wid >> 1) * 16;
    const int m0 = mt * 32 + (wid & 1) * 16;

    const size_t kstride = (size_t)BB * NN * DP;            // elems per k-slice
    const size_t rowA = ((size_t)b * NN + n0 + l15) * DP;   // this lane's A row
    const size_t rowB = ((size_t)b * NN + m0 + l15) * DP;   // this lane's B row

    f32x4 acc[8];
    #pragma unroll
    for (int k = 0; k < 8; ++k)
        #pragma unroll
        for (int i = 0; i < 4; ++i) acc[k][i] = 0.0f;

    #pragma unroll
    for (int k = 0; k < 8; ++k) {
        const __hip_bfloat16* zk = z + (size_t)k * kstride;
        #pragma unroll
        for (int kk = 0; kk < 2; ++kk) {
            const int eo = kk * 32 + q * 8;
            bf16x8 af = *(const bf16x8*)(zk + rowA + eo);
            bf16x8 bf = *(const bf16x8*)(zk + rowB + eo);
            acc[k] = __builtin_amdgcn_mfma_f32_16x16x32_bf16(af, bf, acc[k], 0, 0, 0);
        }
    }

    // store: lane owns col m = m0+l15, rows n = n0 + q*4 + r; all 8 k contiguous
    float* ob = out + (size_t)b * NN * NN * KK;
    #pragma unroll
    for (int r = 0; r < 4; ++r) {
        const int n = n0 + q * 4 + r;
        float* p = ob + ((size_t)n * NN + m0 + l15) * KK;
        *(float4*)p       = make_float4(acc[0][r], acc[1][r], acc[2][r], acc[3][r]);
        *(float4*)(p + 4) = make_float4(acc[4][r], acc[5][r], acc[6][r], acc[7][r]);
    }
}

// ---------------------------------------------------------------------------
extern "C" void kernel_launch(void* const* d_in, const int* in_sizes, int n_in,
                              void* d_out, int out_size, void* d_ws, size_t ws_size,
                              hipStream_t stream)
{
    const float* x    = (const float*)d_in[0];
    const float* W    = (const float*)d_in[1];
    const float* bias = (const float*)d_in[2];
    float* out        = (float*)d_out;
    __hip_bfloat16* z  = (__hip_bfloat16*)d_ws;
    __hip_bfloat16* Wt = (__hip_bfloat16*)((char*)d_ws + Z_BYTES);

    wt_kernel <<<dim3(KK),            dim3(256), 0, stream>>>(W, Wt);
    enc_kernel<<<dim3(BB * NN / 32),  dim3(256), 0, stream>>>(x, Wt, bias, z);
    gram_kernel<<<dim3(BB * 32 * 32), dim3(256), 0, stream>>>(z, out);
}

// Round 4
// 272.025 us; speedup vs baseline: 1.0753x; 1.0753x over previous
//
#include <hip/hip_runtime.h>
#include <hip/hip_bf16.h>

#define BB 16
#define NN 1024
#define DIN 64
#define KK 8
#define DP 64

typedef __bf16 bf16x8 __attribute__((ext_vector_type(8)));
typedef float f32x4 __attribute__((ext_vector_type(4)));
typedef float f32x16 __attribute__((ext_vector_type(16)));

// ws layout: z bf16 [K][B*N][DP]  = 16 MiB at offset 0
//            Wt bf16 [K][DP][DIN] = 64 KiB at offset 16 MiB
#define Z_BYTES (16777216UL)

// ---------------------------------------------------------------------------
// Kernel 0: Wt[k][e][d] = bf16(W[k][d][e])   (8 blocks, one per k)
// ---------------------------------------------------------------------------
__global__ __launch_bounds__(256) void wt_kernel(const float* __restrict__ W,
                                                 __hip_bfloat16* __restrict__ Wt)
{
    __shared__ float Wl[DIN * DP];
    const int k = blockIdx.x;
    const int tid = threadIdx.x;

    const float4* src = (const float4*)(W + (size_t)k * DIN * DP);
    float4* dst = (float4*)Wl;
    #pragma unroll
    for (int i = 0; i < 4; ++i) dst[tid + i * 256] = src[tid + i * 256];
    __syncthreads();

    const int e  = tid >> 2;          // 0..63
    const int dc = (tid & 3) * 16;    // d-chunk
    __hip_bfloat16 v[16];
    #pragma unroll
    for (int i = 0; i < 16; ++i)
        v[i] = __float2bfloat16(Wl[(dc + i) * DP + e]);
    *(uint4*)(Wt + ((size_t)k * DP + e) * DIN + dc)     = *(uint4*)&v[0];
    *(uint4*)(Wt + ((size_t)k * DP + e) * DIN + dc + 8) = *(uint4*)&v[8];
}

// ---------------------------------------------------------------------------
// Kernel 1: z[k][row][e] = relu(sum_d x[row][d] * W[k][d][e] + bias[k][e]), bf16
// (unchanged — validated, MFMA-based)
// ---------------------------------------------------------------------------
__global__ __launch_bounds__(256) void enc_kernel(const float* __restrict__ x,
                                                  const __hip_bfloat16* __restrict__ Wt,
                                                  const float* __restrict__ bias,
                                                  __hip_bfloat16* __restrict__ z)
{
    const int tid  = threadIdx.x;
    const int lane = tid & 63;
    const int wid  = tid >> 6;
    const int l31  = lane & 31;
    const int h    = lane >> 5;
    const int row0 = blockIdx.x * 32;
    const int row  = row0 + l31;

    bf16x8 xb[4];
    #pragma unroll
    for (int kk = 0; kk < 4; ++kk) {
        const float* xp = x + (size_t)row * DIN + kk * 16 + h * 8;
        float4 lo = *(const float4*)xp;
        float4 hi = *(const float4*)(xp + 4);
        bf16x8 t;
        t[0] = (__bf16)lo.x; t[1] = (__bf16)lo.y; t[2] = (__bf16)lo.z; t[3] = (__bf16)lo.w;
        t[4] = (__bf16)hi.x; t[5] = (__bf16)hi.y; t[6] = (__bf16)hi.z; t[7] = (__bf16)hi.w;
        xb[kk] = t;
    }

    #pragma unroll
    for (int a = 0; a < 2; ++a) {
        const int k = wid * 2 + a;
        #pragma unroll
        for (int et = 0; et < 2; ++et) {
            f32x16 acc;
            #pragma unroll
            for (int i = 0; i < 16; ++i) acc[i] = 0.0f;
            const __hip_bfloat16* wp =
                Wt + ((size_t)k * DP + et * 32 + l31) * DIN + h * 8;
            #pragma unroll
            for (int kk = 0; kk < 4; ++kk) {
                bf16x8 wf = *(const bf16x8*)(wp + kk * 16);
                acc = __builtin_amdgcn_mfma_f32_32x32x16_bf16(wf, xb[kk], acc, 0, 0, 0);
            }
            #pragma unroll
            for (int g = 0; g < 4; ++g) {
                const int e0 = et * 32 + 8 * g + 4 * h;
                float4 b4 = *(const float4*)(bias + k * DP + e0);
                union { __hip_bfloat16 b[4]; uint2 u; } pk;
                pk.b[0] = __float2bfloat16(fmaxf(acc[g * 4 + 0] + b4.x, 0.0f));
                pk.b[1] = __float2bfloat16(fmaxf(acc[g * 4 + 1] + b4.y, 0.0f));
                pk.b[2] = __float2bfloat16(fmaxf(acc[g * 4 + 2] + b4.z, 0.0f));
                pk.b[3] = __float2bfloat16(fmaxf(acc[g * 4 + 3] + b4.w, 0.0f));
                *(uint2*)(z + ((size_t)k * BB * NN + row) * DP + e0) = pk.u;
            }
        }
    }
}

// ---------------------------------------------------------------------------
// Kernel 2: R[b][n][m][k] = sum_e z[k][b][n][e] * z[k][b][m][e]
// Compute identical to round 3 (validated): wave = 16n x 16m x 8k,
// mfma_f32_16x16x32_bf16, acc = 8 x f32x4.
// NEW: wave-PRIVATE LDS funnel (no __syncthreads — same-wave DS ordering is
// HW-guaranteed). Scatter k-register tiles into 8 KB LDS with an XOR slot
// swizzle (conflict-free both directions), gather contiguous float4s, emit
// DENSE 1 KB-per-instruction global stores (fill-kernel store pattern).
// Slot map: sigma(n15, m, kh) = n15*32 + m*2 + (kh ^ ((m>>2)&1)).
// ---------------------------------------------------------------------------
__global__ __launch_bounds__(256) void gram_kernel(const __hip_bfloat16* __restrict__ z,
                                                   float* __restrict__ out)
{
    __shared__ __align__(16) float lds[4 * 2048];   // 8 KB per wave

    const int bid = blockIdx.x;
    const int mt  = bid & 31;
    const int nt  = (bid >> 5) & 31;
    const int b   = bid >> 10;
    const int tid  = threadIdx.x;
    const int lane = tid & 63;
    const int wid  = tid >> 6;
    const int l15  = lane & 15;
    const int q    = lane >> 4;       // 0..3

    const int n0 = nt * 32 + (wid >> 1) * 16;
    const int m0 = mt * 32 + (wid & 1) * 16;

    const size_t kstride = (size_t)BB * NN * DP;
    const size_t rowA = ((size_t)b * NN + n0 + l15) * DP;
    const size_t rowB = ((size_t)b * NN + m0 + l15) * DP;

    f32x4 acc[8];
    #pragma unroll
    for (int k = 0; k < 8; ++k)
        #pragma unroll
        for (int i = 0; i < 4; ++i) acc[k][i] = 0.0f;

    #pragma unroll
    for (int k = 0; k < 8; ++k) {
        const __hip_bfloat16* zk = z + (size_t)k * kstride;
        #pragma unroll
        for (int kk = 0; kk < 2; ++kk) {
            const int eo = kk * 32 + q * 8;
            bf16x8 af = *(const bf16x8*)(zk + rowA + eo);
            bf16x8 bf = *(const bf16x8*)(zk + rowB + eo);
            acc[k] = __builtin_amdgcn_mfma_f32_16x16x32_bf16(af, bf, acc[k], 0, 0, 0);
        }
    }

    float* wl = &lds[wid * 2048];

    // scatter: lane (q,l15) owns (n15 = q*4+r, m = l15, kh) -> slot sigma
    const int swz = (l15 >> 2) & 1;
    #pragma unroll
    for (int r = 0; r < 4; ++r) {
        const int n15 = q * 4 + r;
        const int s0 = n15 * 32 + l15 * 2 + swz;        // kh=0: 0 ^ swz
        const int s1 = n15 * 32 + l15 * 2 + (1 ^ swz);  // kh=1
        *(f32x4*)&wl[s0 * 4] = (f32x4){acc[0][r], acc[1][r], acc[2][r], acc[3][r]};
        *(f32x4*)&wl[s1 * 4] = (f32x4){acc[4][r], acc[5][r], acc[6][r], acc[7][r]};
    }

    // gather + dense store: inst i covers rows n15 = 2i+half, 512 B each half
    float* ob = out + (size_t)b * NN * NN * KK;
    const int c    = lane & 31;            // 16-B chunk within a row tile
    const int half = lane >> 5;
    const int cg   = c ^ ((c >> 3) & 1);   // swizzled slot low bits
    #pragma unroll
    for (int i = 0; i < 8; ++i) {
        const int n15 = 2 * i + half;
        f32x4 v = *(const f32x4*)&wl[(n15 * 32 + cg) * 4];
        const int n = n0 + n15;
        float* p = ob + ((size_t)n * NN + m0 + (c >> 1)) * KK + (c & 1) * 4;
        *(f32x4*)p = v;
    }
}

// ---------------------------------------------------------------------------
extern "C" void kernel_launch(void* const* d_in, const int* in_sizes, int n_in,
                              void* d_out, int out_size, void* d_ws, size_t ws_size,
                              hipStream_t stream)
{
    const float* x    = (const float*)d_in[0];
    const float* W    = (const float*)d_in[1];
    const float* bias = (const float*)d_in[2];
    float* out        = (float*)d_out;
    __hip_bfloat16* z  = (__hip_bfloat16*)d_ws;
    __hip_bfloat16* Wt = (__hip_bfloat16*)((char*)d_ws + Z_BYTES);

    wt_kernel <<<dim3(KK),            dim3(256), 0, stream>>>(W, Wt);
    enc_kernel<<<dim3(BB * NN / 32),  dim3(256), 0, stream>>>(x, Wt, bias, z);
    gram_kernel<<<dim3(BB * 32 * 32), dim3(256), 0, stream>>>(z, out);
}

// Round 5
// 236.810 us; speedup vs baseline: 1.2352x; 1.1487x over previous
//
#include <hip/hip_runtime.h>
#include <hip/hip_bf16.h>

#define BB 16
#define NN 1024
#define DIN 64
#define KK 8
#define DP 64

typedef __bf16 bf16x8 __attribute__((ext_vector_type(8)));
typedef float f32x4 __attribute__((ext_vector_type(4)));
typedef float f32x16 __attribute__((ext_vector_type(16)));

// ws layout: z bf16 [K][B*N][DP]  = 16 MiB at offset 0
//            Wt bf16 [K][DP][DIN] = 64 KiB at offset 16 MiB
#define Z_BYTES (16777216UL)

// ---------------------------------------------------------------------------
// Kernel 0: Wt[k][e][d] = bf16(W[k][d][e])   (8 blocks, one per k)
// ---------------------------------------------------------------------------
__global__ __launch_bounds__(256) void wt_kernel(const float* __restrict__ W,
                                                 __hip_bfloat16* __restrict__ Wt)
{
    __shared__ float Wl[DIN * DP];
    const int k = blockIdx.x;
    const int tid = threadIdx.x;

    const float4* src = (const float4*)(W + (size_t)k * DIN * DP);
    float4* dst = (float4*)Wl;
    #pragma unroll
    for (int i = 0; i < 4; ++i) dst[tid + i * 256] = src[tid + i * 256];
    __syncthreads();

    const int e  = tid >> 2;          // 0..63
    const int dc = (tid & 3) * 16;    // d-chunk
    __hip_bfloat16 v[16];
    #pragma unroll
    for (int i = 0; i < 16; ++i)
        v[i] = __float2bfloat16(Wl[(dc + i) * DP + e]);
    *(uint4*)(Wt + ((size_t)k * DP + e) * DIN + dc)     = *(uint4*)&v[0];
    *(uint4*)(Wt + ((size_t)k * DP + e) * DIN + dc + 8) = *(uint4*)&v[8];
}

// ---------------------------------------------------------------------------
// Kernel 1: z[k][row][e] = relu(sum_d x[row][d] * W[k][d][e] + bias[k][e]), bf16
// (unchanged — validated, MFMA-based)
// ---------------------------------------------------------------------------
__global__ __launch_bounds__(256) void enc_kernel(const float* __restrict__ x,
                                                  const __hip_bfloat16* __restrict__ Wt,
                                                  const float* __restrict__ bias,
                                                  __hip_bfloat16* __restrict__ z)
{
    const int tid  = threadIdx.x;
    const int lane = tid & 63;
    const int wid  = tid >> 6;
    const int l31  = lane & 31;
    const int h    = lane >> 5;
    const int row0 = blockIdx.x * 32;
    const int row  = row0 + l31;

    bf16x8 xb[4];
    #pragma unroll
    for (int kk = 0; kk < 4; ++kk) {
        const float* xp = x + (size_t)row * DIN + kk * 16 + h * 8;
        float4 lo = *(const float4*)xp;
        float4 hi = *(const float4*)(xp + 4);
        bf16x8 t;
        t[0] = (__bf16)lo.x; t[1] = (__bf16)lo.y; t[2] = (__bf16)lo.z; t[3] = (__bf16)lo.w;
        t[4] = (__bf16)hi.x; t[5] = (__bf16)hi.y; t[6] = (__bf16)hi.z; t[7] = (__bf16)hi.w;
        xb[kk] = t;
    }

    #pragma unroll
    for (int a = 0; a < 2; ++a) {
        const int k = wid * 2 + a;
        #pragma unroll
        for (int et = 0; et < 2; ++et) {
            f32x16 acc;
            #pragma unroll
            for (int i = 0; i < 16; ++i) acc[i] = 0.0f;
            const __hip_bfloat16* wp =
                Wt + ((size_t)k * DP + et * 32 + l31) * DIN + h * 8;
            #pragma unroll
            for (int kk = 0; kk < 4; ++kk) {
                bf16x8 wf = *(const bf16x8*)(wp + kk * 16);
                acc = __builtin_amdgcn_mfma_f32_32x32x16_bf16(wf, xb[kk], acc, 0, 0, 0);
            }
            #pragma unroll
            for (int g = 0; g < 4; ++g) {
                const int e0 = et * 32 + 8 * g + 4 * h;
                float4 b4 = *(const float4*)(bias + k * DP + e0);
                union { __hip_bfloat16 b[4]; uint2 u; } pk;
                pk.b[0] = __float2bfloat16(fmaxf(acc[g * 4 + 0] + b4.x, 0.0f));
                pk.b[1] = __float2bfloat16(fmaxf(acc[g * 4 + 1] + b4.y, 0.0f));
                pk.b[2] = __float2bfloat16(fmaxf(acc[g * 4 + 2] + b4.z, 0.0f));
                pk.b[3] = __float2bfloat16(fmaxf(acc[g * 4 + 3] + b4.w, 0.0f));
                *(uint2*)(z + ((size_t)k * BB * NN + row) * DP + e0) = pk.u;
            }
        }
    }
}

// ---------------------------------------------------------------------------
// Kernel 2: R[b][n][m][k] = sum_e z[k][b][n][e] * z[k][b][m][e]
// PANEL-PERSISTENT: block = (b, 32 n-rows, m-eighth of 8 tiles). A-fragments
// (8k x 2kk bf16x8 = 64 VGPR) hoisted once; m-loop streams B tiles, computes
// 16 mfma_16x16x32 per wave per tile, funnels through wave-private LDS
// (validated r4 mapping), emits dense 512B-segment stores.
// Occupancy controlled: __launch_bounds__(256,4) => <=128 VGPR, 4 blocks/CU
// resident (LDS 32KB/block), 16 waves/CU.
// XCD grouping: b = bid&15 puts same-b blocks on the same XCD (bid%8=b&7),
// so all blocks of an XCD stream the same 1MB z_b slice -> L2-resident.
// ---------------------------------------------------------------------------
__global__ __launch_bounds__(256, 4) void gram_kernel(const __hip_bfloat16* __restrict__ z,
                                                      float* __restrict__ out)
{
    __shared__ __align__(16) float lds[4 * 2048];   // 8 KB per wave

    const int bid = blockIdx.x;
    const int b   = bid & 15;          // low bits -> XCD grouping by batch
    const int nt  = (bid >> 4) & 31;
    const int mh  = bid >> 9;          // m-eighth: 0..3 (8 tiles each)
    const int tid  = threadIdx.x;
    const int lane = tid & 63;
    const int wid  = tid >> 6;
    const int l15  = lane & 15;
    const int q    = lane >> 4;        // 0..3

    const int n0   = nt * 32 + (wid >> 1) * 16;
    const int msub = (wid & 1) * 16;

    const size_t kstride = (size_t)BB * NN * DP;
    const size_t rowA = ((size_t)b * NN + n0 + l15) * DP;

    // hoist A fragments: af[k][kk] (64 VGPR), reused across all m-tiles
    bf16x8 af[8][2];
    #pragma unroll
    for (int k = 0; k < 8; ++k) {
        const __hip_bfloat16* zk = z + (size_t)k * kstride;
        #pragma unroll
        for (int kk = 0; kk < 2; ++kk)
            af[k][kk] = *(const bf16x8*)(zk + rowA + kk * 32 + q * 8);
    }

    float* wl = &lds[wid * 2048];
    const int swz  = (l15 >> 2) & 1;
    const int c    = lane & 31;
    const int half = lane >> 5;
    const int cg   = c ^ ((c >> 3) & 1);

    float* ob = out + (size_t)b * NN * NN * KK;

    for (int it = 0; it < 8; ++it) {
        const int mt = mh * 8 + it;
        const int m0 = mt * 32 + msub;
        const size_t rowB = ((size_t)b * NN + m0 + l15) * DP;

        f32x4 acc[8];
        #pragma unroll
        for (int k = 0; k < 8; ++k)
            #pragma unroll
            for (int i = 0; i < 4; ++i) acc[k][i] = 0.0f;

        // k-loop: loads consumed immediately (bounded live range)
        #pragma unroll
        for (int k = 0; k < 8; ++k) {
            const __hip_bfloat16* zk = z + (size_t)k * kstride;
            bf16x8 bf0 = *(const bf16x8*)(zk + rowB + q * 8);
            bf16x8 bf1 = *(const bf16x8*)(zk + rowB + 32 + q * 8);
            acc[k] = __builtin_amdgcn_mfma_f32_16x16x32_bf16(af[k][0], bf0, acc[k], 0, 0, 0);
            acc[k] = __builtin_amdgcn_mfma_f32_16x16x32_bf16(af[k][1], bf1, acc[k], 0, 0, 0);
        }

        // wave-private LDS funnel (validated r4 mapping; same-wave DS ordering)
        #pragma unroll
        for (int r = 0; r < 4; ++r) {
            const int n15 = q * 4 + r;
            const int s0 = n15 * 32 + l15 * 2 + swz;
            const int s1 = n15 * 32 + l15 * 2 + (1 ^ swz);
            *(f32x4*)&wl[s0 * 4] = (f32x4){acc[0][r], acc[1][r], acc[2][r], acc[3][r]};
            *(f32x4*)&wl[s1 * 4] = (f32x4){acc[4][r], acc[5][r], acc[6][r], acc[7][r]};
        }

        // gather + dense 512B-segment stores
        #pragma unroll
        for (int i = 0; i < 8; ++i) {
            const int n15 = 2 * i + half;
            f32x4 v = *(const f32x4*)&wl[(n15 * 32 + cg) * 4];
            const int n = n0 + n15;
            float* p = ob + ((size_t)n * NN + m0 + (c >> 1)) * KK + (c & 1) * 4;
            *(f32x4*)p = v;
        }
    }
}

// ---------------------------------------------------------------------------
extern "C" void kernel_launch(void* const* d_in, const int* in_sizes, int n_in,
                              void* d_out, int out_size, void* d_ws, size_t ws_size,
                              hipStream_t stream)
{
    const float* x    = (const float*)d_in[0];
    const float* W    = (const float*)d_in[1];
    const float* bias = (const float*)d_in[2];
    float* out        = (float*)d_out;
    __hip_bfloat16* z  = (__hip_bfloat16*)d_ws;
    __hip_bfloat16* Wt = (__hip_bfloat16*)((char*)d_ws + Z_BYTES);

    wt_kernel <<<dim3(KK),           dim3(256), 0, stream>>>(W, Wt);
    enc_kernel<<<dim3(BB * NN / 32), dim3(256), 0, stream>>>(x, Wt, bias, z);
    gram_kernel<<<dim3(16 * 32 * 4), dim3(256), 0, stream>>>(z, out);
}

// Round 6
// 184.225 us; speedup vs baseline: 1.5878x; 1.2854x over previous
//
#include <hip/hip_runtime.h>
#include <hip/hip_bf16.h>

#define BB 16
#define NN 1024
#define DIN 64
#define KK 8
#define DP 64

typedef __bf16 bf16x8 __attribute__((ext_vector_type(8)));
typedef float f32x16 __attribute__((ext_vector_type(16)));

// ws layout: z bf16 [K][B*N][DP]  = 16 MiB at offset 0
//            Wt bf16 [K][DP][DIN] = 64 KiB at offset 16 MiB
#define Z_BYTES (16777216UL)

// ---------------------------------------------------------------------------
// Kernel 0: Wt[k][e][d] = bf16(W[k][d][e])   (8 blocks, one per k)
// ---------------------------------------------------------------------------
__global__ __launch_bounds__(256) void wt_kernel(const float* __restrict__ W,
                                                 __hip_bfloat16* __restrict__ Wt)
{
    __shared__ float Wl[DIN * DP];
    const int k = blockIdx.x;
    const int tid = threadIdx.x;

    const float4* src = (const float4*)(W + (size_t)k * DIN * DP);
    float4* dst = (float4*)Wl;
    #pragma unroll
    for (int i = 0; i < 4; ++i) dst[tid + i * 256] = src[tid + i * 256];
    __syncthreads();

    const int e  = tid >> 2;          // 0..63
    const int dc = (tid & 3) * 16;    // d-chunk
    __hip_bfloat16 v[16];
    #pragma unroll
    for (int i = 0; i < 16; ++i)
        v[i] = __float2bfloat16(Wl[(dc + i) * DP + e]);
    *(uint4*)(Wt + ((size_t)k * DP + e) * DIN + dc)     = *(uint4*)&v[0];
    *(uint4*)(Wt + ((size_t)k * DP + e) * DIN + dc + 8) = *(uint4*)&v[8];
}

// ---------------------------------------------------------------------------
// Kernel 1: z[k][row][e] = relu(sum_d x[row][d] * W[k][d][e] + bias[k][e]), bf16
// (validated MFMA enc, unchanged from rounds 2-5)
// ---------------------------------------------------------------------------
__global__ __launch_bounds__(256) void enc_kernel(const float* __restrict__ x,
                                                  const __hip_bfloat16* __restrict__ Wt,
                                                  const float* __restrict__ bias,
                                                  __hip_bfloat16* __restrict__ z)
{
    const int tid  = threadIdx.x;
    const int lane = tid & 63;
    const int wid  = tid >> 6;
    const int l31  = lane & 31;
    const int h    = lane >> 5;
    const int row0 = blockIdx.x * 32;
    const int row  = row0 + l31;

    bf16x8 xb[4];
    #pragma unroll
    for (int kk = 0; kk < 4; ++kk) {
        const float* xp = x + (size_t)row * DIN + kk * 16 + h * 8;
        float4 lo = *(const float4*)xp;
        float4 hi = *(const float4*)(xp + 4);
        bf16x8 t;
        t[0] = (__bf16)lo.x; t[1] = (__bf16)lo.y; t[2] = (__bf16)lo.z; t[3] = (__bf16)lo.w;
        t[4] = (__bf16)hi.x; t[5] = (__bf16)hi.y; t[6] = (__bf16)hi.z; t[7] = (__bf16)hi.w;
        xb[kk] = t;
    }

    #pragma unroll
    for (int a = 0; a < 2; ++a) {
        const int k = wid * 2 + a;
        #pragma unroll
        for (int et = 0; et < 2; ++et) {
            f32x16 acc;
            #pragma unroll
            for (int i = 0; i < 16; ++i) acc[i] = 0.0f;
            const __hip_bfloat16* wp =
                Wt + ((size_t)k * DP + et * 32 + l31) * DIN + h * 8;
            #pragma unroll
            for (int kk = 0; kk < 4; ++kk) {
                bf16x8 wf = *(const bf16x8*)(wp + kk * 16);
                acc = __builtin_amdgcn_mfma_f32_32x32x16_bf16(wf, xb[kk], acc, 0, 0, 0);
            }
            #pragma unroll
            for (int g = 0; g < 4; ++g) {
                const int e0 = et * 32 + 8 * g + 4 * h;
                float4 b4 = *(const float4*)(bias + k * DP + e0);
                union { __hip_bfloat16 b[4]; uint2 u; } pk;
                pk.b[0] = __float2bfloat16(fmaxf(acc[g * 4 + 0] + b4.x, 0.0f));
                pk.b[1] = __float2bfloat16(fmaxf(acc[g * 4 + 1] + b4.y, 0.0f));
                pk.b[2] = __float2bfloat16(fmaxf(acc[g * 4 + 2] + b4.z, 0.0f));
                pk.b[3] = __float2bfloat16(fmaxf(acc[g * 4 + 3] + b4.w, 0.0f));
                *(uint2*)(z + ((size_t)k * BB * NN + row) * DP + e0) = pk.u;
            }
        }
    }
}

// ---------------------------------------------------------------------------
// Kernel 2: BYTE-IDENTICAL to round 1's gram (the fastest measured: ~145us).
// R[b][n][m][k] = sum_e z[k][b][n][e] * z[k][b][m][e]
// Wave w: attrs 2w,2w+1 via mfma_32x32x16; block-shared LDS funnel (pad-9),
// dense 1KB-per-row coalesced stores.
// ---------------------------------------------------------------------------
__global__ __launch_bounds__(256) void gram_kernel(const __hip_bfloat16* __restrict__ z,
                                                   float* __restrict__ out)
{
    __shared__ float tile[32 * 32 * 9];  // k padded 8->9: conflict-free stride

    const int bid = blockIdx.x;
    const int mt  = bid & 31;
    const int nt  = (bid >> 5) & 31;
    const int b   = bid >> 10;
    const int tid  = threadIdx.x;
    const int lane = tid & 63;
    const int wid  = tid >> 6;
    const int k0   = wid * 2;

    const int rrow = lane & 31;   // row within 32-tile (A: n, B: m)
    const int h    = lane >> 5;   // K-half selector

    const size_t kslice = (size_t)BB * NN * DP;
    const size_t baseA0 = (((size_t)(k0 * BB) + b) * NN + nt * 32 + rrow) * DP + h * 8;
    const size_t baseB0 = (((size_t)(k0 * BB) + b) * NN + mt * 32 + rrow) * DP + h * 8;
    const size_t baseA1 = baseA0 + kslice;
    const size_t baseB1 = baseB0 + kslice;

    f32x16 acc0, acc1;
    #pragma unroll
    for (int i = 0; i < 16; ++i) { acc0[i] = 0.0f; acc1[i] = 0.0f; }

    #pragma unroll
    for (int kk = 0; kk < 4; ++kk) {
        bf16x8 a0 = *(const bf16x8*)(z + baseA0 + kk * 16);
        bf16x8 b0 = *(const bf16x8*)(z + baseB0 + kk * 16);
        bf16x8 a1 = *(const bf16x8*)(z + baseA1 + kk * 16);
        bf16x8 b1 = *(const bf16x8*)(z + baseB1 + kk * 16);
        acc0 = __builtin_amdgcn_mfma_f32_32x32x16_bf16(a0, b0, acc0, 0, 0, 0);
        acc1 = __builtin_amdgcn_mfma_f32_32x32x16_bf16(a1, b1, acc1, 0, 0, 0);
    }

    // scatter into LDS tile [n][m][k(pad 9)]
    #pragma unroll
    for (int r = 0; r < 16; ++r) {
        int n = (r & 3) + 8 * (r >> 2) + 4 * h;
        int off = (n * 32 + rrow) * 9;
        tile[off + k0]     = acc0[r];
        tile[off + k0 + 1] = acc1[r];
    }
    __syncthreads();

    // coalesced write-out: per output row n, 32 m * 8 k = 256 contiguous floats
    float* op = out + (((size_t)b * NN + nt * 32) * NN + (size_t)mt * 32) * KK;
    #pragma unroll
    for (int j = 0; j < 8; ++j) {
        int flat = j * 256 + tid;     // float4 index within the 32x32x8 tile
        int n  = flat >> 6;           // 64 float4 per row
        int c4 = flat & 63;           // c4*4 = m*8 + kq
        int m  = c4 >> 1;
        int kq = (c4 & 1) * 4;
        int off = (n * 32 + m) * 9 + kq;
        float4 v = make_float4(tile[off], tile[off + 1], tile[off + 2], tile[off + 3]);
        *(float4*)(op + (size_t)n * NN * KK + c4 * 4) = v;
    }
}

// ---------------------------------------------------------------------------
extern "C" void kernel_launch(void* const* d_in, const int* in_sizes, int n_in,
                              void* d_out, int out_size, void* d_ws, size_t ws_size,
                              hipStream_t stream)
{
    const float* x    = (const float*)d_in[0];
    const float* W    = (const float*)d_in[1];
    const float* bias = (const float*)d_in[2];
    float* out        = (float*)d_out;
    __hip_bfloat16* z  = (__hip_bfloat16*)d_ws;
    __hip_bfloat16* Wt = (__hip_bfloat16*)((char*)d_ws + Z_BYTES);

    wt_kernel <<<dim3(KK),            dim3(256), 0, stream>>>(W, Wt);
    enc_kernel<<<dim3(BB * NN / 32),  dim3(256), 0, stream>>>(x, Wt, bias, z);
    gram_kernel<<<dim3(BB * 32 * 32), dim3(256), 0, stream>>>(z, out);
}

// Round 7
// 131.516 us; speedup vs baseline: 2.2242x; 1.4008x over previous
//
#include <hip/hip_runtime.h>
#include <hip/hip_bf16.h>

#define BB 16
#define NN 1024
#define DIN 64
#define KK 8
#define DP 64

typedef __bf16 bf16x8 __attribute__((ext_vector_type(8)));
typedef float f32x16 __attribute__((ext_vector_type(16)));

// ws layout: z bf16 [K][B*N][DP]  = 16 MiB at offset 0
//            Wt bf16 [K][DP][DIN] = 64 KiB at offset 16 MiB
#define Z_BYTES (16777216UL)

// ---------------------------------------------------------------------------
// Kernel 0: Wt[k][e][d] = bf16(W[k][d][e])   (8 blocks, one per k)
// ---------------------------------------------------------------------------
__global__ __launch_bounds__(256) void wt_kernel(const float* __restrict__ W,
                                                 __hip_bfloat16* __restrict__ Wt)
{
    __shared__ float Wl[DIN * DP];
    const int k = blockIdx.x;
    const int tid = threadIdx.x;

    const float4* src = (const float4*)(W + (size_t)k * DIN * DP);
    float4* dst = (float4*)Wl;
    #pragma unroll
    for (int i = 0; i < 4; ++i) dst[tid + i * 256] = src[tid + i * 256];
    __syncthreads();

    const int e  = tid >> 2;          // 0..63
    const int dc = (tid & 3) * 16;    // d-chunk
    __hip_bfloat16 v[16];
    #pragma unroll
    for (int i = 0; i < 16; ++i)
        v[i] = __float2bfloat16(Wl[(dc + i) * DP + e]);
    *(uint4*)(Wt + ((size_t)k * DP + e) * DIN + dc)     = *(uint4*)&v[0];
    *(uint4*)(Wt + ((size_t)k * DP + e) * DIN + dc + 8) = *(uint4*)&v[8];
}

// ---------------------------------------------------------------------------
// Kernel 1: z[k][row][e] = relu(sum_d x[row][d] * W[k][d][e] + bias[k][e]), bf16
// (validated MFMA enc, unchanged)
// ---------------------------------------------------------------------------
__global__ __launch_bounds__(256) void enc_kernel(const float* __restrict__ x,
                                                  const __hip_bfloat16* __restrict__ Wt,
                                                  const float* __restrict__ bias,
                                                  __hip_bfloat16* __restrict__ z)
{
    const int tid  = threadIdx.x;
    const int lane = tid & 63;
    const int wid  = tid >> 6;
    const int l31  = lane & 31;
    const int h    = lane >> 5;
    const int row0 = blockIdx.x * 32;
    const int row  = row0 + l31;

    bf16x8 xb[4];
    #pragma unroll
    for (int kk = 0; kk < 4; ++kk) {
        const float* xp = x + (size_t)row * DIN + kk * 16 + h * 8;
        float4 lo = *(const float4*)xp;
        float4 hi = *(const float4*)(xp + 4);
        bf16x8 t;
        t[0] = (__bf16)lo.x; t[1] = (__bf16)lo.y; t[2] = (__bf16)lo.z; t[3] = (__bf16)lo.w;
        t[4] = (__bf16)hi.x; t[5] = (__bf16)hi.y; t[6] = (__bf16)hi.z; t[7] = (__bf16)hi.w;
        xb[kk] = t;
    }

    #pragma unroll
    for (int a = 0; a < 2; ++a) {
        const int k = wid * 2 + a;
        #pragma unroll
        for (int et = 0; et < 2; ++et) {
            f32x16 acc;
            #pragma unroll
            for (int i = 0; i < 16; ++i) acc[i] = 0.0f;
            const __hip_bfloat16* wp =
                Wt + ((size_t)k * DP + et * 32 + l31) * DIN + h * 8;
            #pragma unroll
            for (int kk = 0; kk < 4; ++kk) {
                bf16x8 wf = *(const bf16x8*)(wp + kk * 16);
                acc = __builtin_amdgcn_mfma_f32_32x32x16_bf16(wf, xb[kk], acc, 0, 0, 0);
            }
            #pragma unroll
            for (int g = 0; g < 4; ++g) {
                const int e0 = et * 32 + 8 * g + 4 * h;
                float4 b4 = *(const float4*)(bias + k * DP + e0);
                union { __hip_bfloat16 b[4]; uint2 u; } pk;
                pk.b[0] = __float2bfloat16(fmaxf(acc[g * 4 + 0] + b4.x, 0.0f));
                pk.b[1] = __float2bfloat16(fmaxf(acc[g * 4 + 1] + b4.y, 0.0f));
                pk.b[2] = __float2bfloat16(fmaxf(acc[g * 4 + 2] + b4.z, 0.0f));
                pk.b[3] = __float2bfloat16(fmaxf(acc[g * 4 + 3] + b4.w, 0.0f));
                *(uint2*)(z + ((size_t)k * BB * NN + row) * DP + e0) = pk.u;
            }
        }
    }
}

// ---------------------------------------------------------------------------
// Kernel 2: r1's validated gram structure + PERSISTENCE.
// Block = (b, nt, m-eighth): A-frags hoisted once (32 VGPR), 8-iter m-loop.
// Per iter: issue NEXT tile's B loads early (in flight across the funnel
// phase), 8 mfma_32x32x16 (2 attrs/wave), r1's exact pad-9 LDS funnel,
// dense 1KB-row stores. Grid = 16*32*4 = 2048. b in low bits -> per-XCD
// z_b L2 residency.
// ---------------------------------------------------------------------------
__global__ __launch_bounds__(256) void gram_kernel(const __hip_bfloat16* __restrict__ z,
                                                   float* __restrict__ out)
{
    __shared__ float tile[32 * 32 * 9];

    const int bid = blockIdx.x;
    const int b   = bid & 15;
    const int nt  = (bid >> 4) & 31;
    const int mh  = bid >> 9;          // 0..3
    const int tid  = threadIdx.x;
    const int lane = tid & 63;
    const int wid  = tid >> 6;
    const int k0   = wid * 2;
    const int rrow = lane & 31;
    const int h    = lane >> 5;

    const size_t kslice  = (size_t)BB * NN * DP;
    const size_t rowbase = ((size_t)k0 * BB + b) * NN;   // k0-slice, batch b

    // hoist A fragments: 2 attrs x 4 kk = 32 VGPR, reused for all 8 m-tiles
    bf16x8 a0[4], a1[4];
    {
        const size_t baseA0 = (rowbase + nt * 32 + rrow) * DP + h * 8;
        #pragma unroll
        for (int kk = 0; kk < 4; ++kk) {
            a0[kk] = *(const bf16x8*)(z + baseA0 + kk * 16);
            a1[kk] = *(const bf16x8*)(z + baseA0 + kslice + kk * 16);
        }
    }

    // prefetch B for it=0
    bf16x8 b0[4], b1[4];
    {
        const size_t baseB0 = (rowbase + (size_t)(mh * 8) * 32 + rrow) * DP + h * 8;
        #pragma unroll
        for (int kk = 0; kk < 4; ++kk) {
            b0[kk] = *(const bf16x8*)(z + baseB0 + kk * 16);
            b1[kk] = *(const bf16x8*)(z + baseB0 + kslice + kk * 16);
        }
    }

    #pragma unroll 1
    for (int it = 0; it < 8; ++it) {
        const int mt = mh * 8 + it;

        // issue next tile's B loads FIRST — latency hides under MFMA + funnel
        bf16x8 nb0[4], nb1[4];
        {
            const int itn = (it < 7) ? it + 1 : 7;
            const size_t baseB0 = (rowbase + (size_t)(mh * 8 + itn) * 32 + rrow) * DP + h * 8;
            #pragma unroll
            for (int kk = 0; kk < 4; ++kk) {
                nb0[kk] = *(const bf16x8*)(z + baseB0 + kk * 16);
                nb1[kk] = *(const bf16x8*)(z + baseB0 + kslice + kk * 16);
            }
        }

        f32x16 acc0, acc1;
        #pragma unroll
        for (int i = 0; i < 16; ++i) { acc0[i] = 0.0f; acc1[i] = 0.0f; }
        #pragma unroll
        for (int kk = 0; kk < 4; ++kk) {
            acc0 = __builtin_amdgcn_mfma_f32_32x32x16_bf16(a0[kk], b0[kk], acc0, 0, 0, 0);
            acc1 = __builtin_amdgcn_mfma_f32_32x32x16_bf16(a1[kk], b1[kk], acc1, 0, 0, 0);
        }

        // scatter into LDS tile [n][m][k pad 9]  (r1-validated mapping)
        #pragma unroll
        for (int r = 0; r < 16; ++r) {
            int n = (r & 3) + 8 * (r >> 2) + 4 * h;
            int off = (n * 32 + rrow) * 9;
            tile[off + k0]     = acc0[r];
            tile[off + k0 + 1] = acc1[r];
        }
        __syncthreads();

        // gather + dense 1KB-per-row stores  (r1-validated mapping)
        float* op = out + (((size_t)b * NN + nt * 32) * NN + (size_t)mt * 32) * KK;
        #pragma unroll
        for (int j = 0; j < 8; ++j) {
            int flat = j * 256 + tid;
            int n  = flat >> 6;
            int c4 = flat & 63;
            int m  = c4 >> 1;
            int kq = (c4 & 1) * 4;
            int off = (n * 32 + m) * 9 + kq;
            float4 v = make_float4(tile[off], tile[off + 1], tile[off + 2], tile[off + 3]);
            *(float4*)(op + (size_t)n * NN * KK + c4 * 4) = v;
        }
        __syncthreads();

        // rotate prefetched B into place (vmcnt wait lands here, fully hidden)
        #pragma unroll
        for (int kk = 0; kk < 4; ++kk) { b0[kk] = nb0[kk]; b1[kk] = nb1[kk]; }
    }
}

// ---------------------------------------------------------------------------
extern "C" void kernel_launch(void* const* d_in, const int* in_sizes, int n_in,
                              void* d_out, int out_size, void* d_ws, size_t ws_size,
                              hipStream_t stream)
{
    const float* x    = (const float*)d_in[0];
    const float* W    = (const float*)d_in[1];
    const float* bias = (const float*)d_in[2];
    float* out        = (float*)d_out;
    __hip_bfloat16* z  = (__hip_bfloat16*)d_ws;
    __hip_bfloat16* Wt = (__hip_bfloat16*)((char*)d_ws + Z_BYTES);

    wt_kernel <<<dim3(KK),           dim3(256), 0, stream>>>(W, Wt);
    enc_kernel<<<dim3(BB * NN / 32), dim3(256), 0, stream>>>(x, Wt, bias, z);
    gram_kernel<<<dim3(16 * 32 * 4), dim3(256), 0, stream>>>(z, out);
}

// Round 8
// 125.127 us; speedup vs baseline: 2.3377x; 1.0511x over previous
//
#include <hip/hip_runtime.h>
#include <hip/hip_bf16.h>

#define BB 16
#define NN 1024
#define DIN 64
#define KK 8
#define DP 64

typedef __bf16 bf16x8 __attribute__((ext_vector_type(8)));
typedef float f32x16 __attribute__((ext_vector_type(16)));

// ws layout: z bf16 [K][B*N][DP]  = 16 MiB at offset 0
//            Wt bf16 [K][DP][DIN] = 64 KiB at offset 16 MiB
#define Z_BYTES (16777216UL)

// ---------------------------------------------------------------------------
// Kernel 0: Wt[k][e][d] = bf16(W[k][d][e])   (8 blocks, one per k)
// ---------------------------------------------------------------------------
__global__ __launch_bounds__(256) void wt_kernel(const float* __restrict__ W,
                                                 __hip_bfloat16* __restrict__ Wt)
{
    __shared__ float Wl[DIN * DP];
    const int k = blockIdx.x;
    const int tid = threadIdx.x;

    const float4* src = (const float4*)(W + (size_t)k * DIN * DP);
    float4* dst = (float4*)Wl;
    #pragma unroll
    for (int i = 0; i < 4; ++i) dst[tid + i * 256] = src[tid + i * 256];
    __syncthreads();

    const int e  = tid >> 2;          // 0..63
    const int dc = (tid & 3) * 16;    // d-chunk
    __hip_bfloat16 v[16];
    #pragma unroll
    for (int i = 0; i < 16; ++i)
        v[i] = __float2bfloat16(Wl[(dc + i) * DP + e]);
    *(uint4*)(Wt + ((size_t)k * DP + e) * DIN + dc)     = *(uint4*)&v[0];
    *(uint4*)(Wt + ((size_t)k * DP + e) * DIN + dc + 8) = *(uint4*)&v[8];
}

// ---------------------------------------------------------------------------
// Kernel 1: z[k][row][e] = relu(sum_d x[row][d] * W[k][d][e] + bias[k][e]), bf16
// (validated MFMA enc, unchanged)
// ---------------------------------------------------------------------------
__global__ __launch_bounds__(256) void enc_kernel(const float* __restrict__ x,
                                                  const __hip_bfloat16* __restrict__ Wt,
                                                  const float* __restrict__ bias,
                                                  __hip_bfloat16* __restrict__ z)
{
    const int tid  = threadIdx.x;
    const int lane = tid & 63;
    const int wid  = tid >> 6;
    const int l31  = lane & 31;
    const int h    = lane >> 5;
    const int row0 = blockIdx.x * 32;
    const int row  = row0 + l31;

    bf16x8 xb[4];
    #pragma unroll
    for (int kk = 0; kk < 4; ++kk) {
        const float* xp = x + (size_t)row * DIN + kk * 16 + h * 8;
        float4 lo = *(const float4*)xp;
        float4 hi = *(const float4*)(xp + 4);
        bf16x8 t;
        t[0] = (__bf16)lo.x; t[1] = (__bf16)lo.y; t[2] = (__bf16)lo.z; t[3] = (__bf16)lo.w;
        t[4] = (__bf16)hi.x; t[5] = (__bf16)hi.y; t[6] = (__bf16)hi.z; t[7] = (__bf16)hi.w;
        xb[kk] = t;
    }

    #pragma unroll
    for (int a = 0; a < 2; ++a) {
        const int k = wid * 2 + a;
        #pragma unroll
        for (int et = 0; et < 2; ++et) {
            f32x16 acc;
            #pragma unroll
            for (int i = 0; i < 16; ++i) acc[i] = 0.0f;
            const __hip_bfloat16* wp =
                Wt + ((size_t)k * DP + et * 32 + l31) * DIN + h * 8;
            #pragma unroll
            for (int kk = 0; kk < 4; ++kk) {
                bf16x8 wf = *(const bf16x8*)(wp + kk * 16);
                acc = __builtin_amdgcn_mfma_f32_32x32x16_bf16(wf, xb[kk], acc, 0, 0, 0);
            }
            #pragma unroll
            for (int g = 0; g < 4; ++g) {
                const int e0 = et * 32 + 8 * g + 4 * h;
                float4 b4 = *(const float4*)(bias + k * DP + e0);
                union { __hip_bfloat16 b[4]; uint2 u; } pk;
                pk.b[0] = __float2bfloat16(fmaxf(acc[g * 4 + 0] + b4.x, 0.0f));
                pk.b[1] = __float2bfloat16(fmaxf(acc[g * 4 + 1] + b4.y, 0.0f));
                pk.b[2] = __float2bfloat16(fmaxf(acc[g * 4 + 2] + b4.z, 0.0f));
                pk.b[3] = __float2bfloat16(fmaxf(acc[g * 4 + 3] + b4.w, 0.0f));
                *(uint2*)(z + ((size_t)k * BB * NN + row) * DP + e0) = pk.u;
            }
        }
    }
}

// ---------------------------------------------------------------------------
// Kernel 2: persistent gram, REGISTER-DIET edition for 32 waves/CU.
// Block = 512 threads = 8 waves, ONE attribute per wave (acc 16 + A 16 +
// B-jit 16 VGPR ~= 60 total, __launch_bounds__(512,8) => 8 waves/SIMD).
// Block = (b, nt, m-eighth); A hoisted once; 8-iter m-loop; B loaded JIT
// (32 waves/CU TLP hides L2 latency). r1-validated pad-9 funnel + dense
// 1KB-row stores (gather re-indexed for 512 threads).
// ---------------------------------------------------------------------------
__global__ __launch_bounds__(512, 8) void gram_kernel(const __hip_bfloat16* __restrict__ z,
                                                      float* __restrict__ out)
{
    __shared__ float tile[32 * 32 * 9];   // 36 KB

    const int bid = blockIdx.x;
    const int b   = bid & 15;
    const int nt  = (bid >> 4) & 31;
    const int mh  = bid >> 9;             // 0..3
    const int tid  = threadIdx.x;
    const int lane = tid & 63;
    const int k    = tid >> 6;            // wave id == attribute
    const int rrow = lane & 31;
    const int h    = lane >> 5;

    const size_t rowbase = ((size_t)k * BB + b) * NN;   // this attr's slice

    // hoist A fragments: 4 x bf16x8 = 16 VGPR, reused for all 8 m-tiles
    bf16x8 a0[4];
    {
        const size_t baseA = (rowbase + nt * 32 + rrow) * DP + h * 8;
        #pragma unroll
        for (int kk = 0; kk < 4; ++kk)
            a0[kk] = *(const bf16x8*)(z + baseA + kk * 16);
    }

    #pragma unroll 1
    for (int it = 0; it < 8; ++it) {
        const int mt = mh * 8 + it;

        // B loaded just-in-time (16 VGPR transient; TLP covers latency)
        const size_t baseB = (rowbase + (size_t)mt * 32 + rrow) * DP + h * 8;
        bf16x8 b0[4];
        #pragma unroll
        for (int kk = 0; kk < 4; ++kk)
            b0[kk] = *(const bf16x8*)(z + baseB + kk * 16);

        f32x16 acc;
        #pragma unroll
        for (int i = 0; i < 16; ++i) acc[i] = 0.0f;
        #pragma unroll
        for (int kk = 0; kk < 4; ++kk)
            acc = __builtin_amdgcn_mfma_f32_32x32x16_bf16(a0[kk], b0[kk], acc, 0, 0, 0);

        // scatter into LDS tile [n][m][k pad 9] — bank (9*rrow+k)%32:
        // conflict-free per half-wave, 2-way across halves (free)
        #pragma unroll
        for (int r = 0; r < 16; ++r) {
            int n = (r & 3) + 8 * (r >> 2) + 4 * h;
            tile[(n * 32 + rrow) * 9 + k] = acc[r];
        }
        __syncthreads();

        // gather + dense 1KB-per-row stores (r1-validated mapping, 512 thr)
        float* op = out + (((size_t)b * NN + nt * 32) * NN + (size_t)mt * 32) * KK;
        #pragma unroll
        for (int j = 0; j < 4; ++j) {
            int flat = j * 512 + tid;     // float4 index in 32x32x8 tile
            int n  = flat >> 6;
            int c4 = flat & 63;
            int m  = c4 >> 1;
            int kq = (c4 & 1) * 4;
            int off = (n * 32 + m) * 9 + kq;
            float4 v = make_float4(tile[off], tile[off + 1], tile[off + 2], tile[off + 3]);
            *(float4*)(op + (size_t)n * NN * KK + c4 * 4) = v;
        }
        __syncthreads();
    }
}

// ---------------------------------------------------------------------------
extern "C" void kernel_launch(void* const* d_in, const int* in_sizes, int n_in,
                              void* d_out, int out_size, void* d_ws, size_t ws_size,
                              hipStream_t stream)
{
    const float* x    = (const float*)d_in[0];
    const float* W    = (const float*)d_in[1];
    const float* bias = (const float*)d_in[2];
    float* out        = (float*)d_out;
    __hip_bfloat16* z  = (__hip_bfloat16*)d_ws;
    __hip_bfloat16* Wt = (__hip_bfloat16*)((char*)d_ws + Z_BYTES);

    wt_kernel <<<dim3(KK),           dim3(256), 0, stream>>>(W, Wt);
    enc_kernel<<<dim3(BB * NN / 32), dim3(256), 0, stream>>>(x, Wt, bias, z);
    gram_kernel<<<dim3(16 * 32 * 4), dim3(512), 0, stream>>>(z, out);
}